// Round 6
// baseline (1073.752 us; speedup 1.0000x reference)
//
#include <hip/hip_runtime.h>
#include <cstdint>
#include <cstddef>

// N=100000, E=20000, P=1600000, din=128, dh=64, H=4, DCAT=512, C=40
static constexpr int DIN = 128;
static constexpr int DH = 64;
static constexpr int NH = 4;
static constexpr int DCAT = 512;
static constexpr int NC = 40;
static constexpr int E_CONST = 20000;
static constexpr int SCAN_CHUNK = 2048;
static constexpr int NXCD = 8;
static constexpr int BIN_CHUNK = 8192;

typedef unsigned short u16;
typedef __attribute__((ext_vector_type(4))) unsigned short u16x4;
typedef __attribute__((ext_vector_type(8))) unsigned short u16x8;
typedef __attribute__((ext_vector_type(8))) short bf16x8;
typedef __attribute__((ext_vector_type(4))) float f32x4;

static __device__ __forceinline__ float bf2f(u16 u) {
    union { unsigned int i; float f; } x;
    x.i = ((unsigned int)u) << 16;
    return x.f;
}
static __device__ __forceinline__ u16 f2bf(float f) {
    union { float f; unsigned int i; } x;
    x.f = f;
    unsigned int r = x.i + 0x7fffu + ((x.i >> 16) & 1u);
    return (u16)(r >> 16);
}

// ---------------- CSR build (XCD-binned: all writes to a dest line come from one XCD) ----------------

__global__ void k_count_binned(const int* __restrict__ pe, const int* __restrict__ pv,
                               int* __restrict__ deg_e, int* __restrict__ deg_v,
                               int P, int E, int N) {
    int g = blockIdx.x & 7;
    int chunk = blockIdx.x >> 3;
    int lo_e = g * E / NXCD, hi_e = (g + 1) * E / NXCD;
    int lo_v = g * N / NXCD, hi_v = (g + 1) * N / NXCD;
    int p0 = chunk * BIN_CHUNK;
    int p1 = p0 + BIN_CHUNK < P ? p0 + BIN_CHUNK : P;
    for (int p = p0 + threadIdx.x; p < p1; p += 256) {
        int e = pe[p];
        if (e >= lo_e && e < hi_e) atomicAdd(&deg_e[e], 1);
        int v = pv[p];
        if (v >= lo_v && v < hi_v) atomicAdd(&deg_v[v], 1);
    }
}

__global__ void k_scatter_binned(const int* __restrict__ pe, const int* __restrict__ pv,
                                 const int* __restrict__ start_e, const int* __restrict__ start_v,
                                 int* __restrict__ cur_e, int* __restrict__ cur_v,
                                 int* __restrict__ csr_e_v, int* __restrict__ csr_v_e,
                                 int P, int E, int N) {
    int g = blockIdx.x & 7;
    int chunk = blockIdx.x >> 3;
    int lo_e = g * E / NXCD, hi_e = (g + 1) * E / NXCD;
    int lo_v = g * N / NXCD, hi_v = (g + 1) * N / NXCD;
    int p0 = chunk * BIN_CHUNK;
    int p1 = p0 + BIN_CHUNK < P ? p0 + BIN_CHUNK : P;
    for (int p = p0 + threadIdx.x; p < p1; p += 256) {
        int e = pe[p];
        int v = pv[p];
        if (e >= lo_e && e < hi_e) {
            int ie = atomicAdd(&cur_e[e], 1);
            csr_e_v[start_e[e] + ie] = v;
        }
        if (v >= lo_v && v < hi_v) {
            int iv = atomicAdd(&cur_v[v], 1);
            csr_v_e[start_v[v] + iv] = e;
        }
    }
}

// multi-block scan: phase 1 — per-block sums
__global__ void k_scan1(const int* __restrict__ in, int* __restrict__ part, int n) {
    __shared__ int wsum[4];
    int tid = threadIdx.x, lane = tid & 63, w = tid >> 6;
    int base = blockIdx.x * SCAN_CHUNK + tid * 8;
    int s = 0;
    #pragma unroll
    for (int j = 0; j < 8; ++j)
        if (base + j < n) s += in[base + j];
    #pragma unroll
    for (int off = 32; off >= 1; off >>= 1) s += __shfl_xor(s, off);
    if (lane == 0) wsum[w] = s;
    __syncthreads();
    if (tid == 0) part[blockIdx.x] = wsum[0] + wsum[1] + wsum[2] + wsum[3];
}

// phase 2 — single wave exclusive scan of partials (nb <= 64), part[nb]=total
__global__ void k_scan2(int* __restrict__ part, int nb) {
    int tid = threadIdx.x;
    int v = (tid < nb) ? part[tid] : 0;
    int incl = v;
    #pragma unroll
    for (int off = 1; off < 64; off <<= 1) {
        int t = __shfl_up(incl, off);
        if (tid >= off) incl += t;
    }
    if (tid < nb) part[tid] = incl - v;
    if (tid == 63) part[nb] = incl;
}

// phase 3 — rescan each chunk, add block offset
__global__ void k_scan3(const int* __restrict__ in, const int* __restrict__ part,
                        int* __restrict__ out, int n, int nb) {
    __shared__ int wsum[4];
    int tid = threadIdx.x, lane = tid & 63, w = tid >> 6;
    int base = blockIdx.x * SCAN_CHUNK + tid * 8;
    int e[8];
    int s = 0;
    #pragma unroll
    for (int j = 0; j < 8; ++j) {
        e[j] = (base + j < n) ? in[base + j] : 0;
        s += e[j];
    }
    int incl = s;
    #pragma unroll
    for (int off = 1; off < 64; off <<= 1) {
        int t = __shfl_up(incl, off);
        if (lane >= off) incl += t;
    }
    if (lane == 63) wsum[w] = incl;
    __syncthreads();
    int woff = 0;
    for (int k = 0; k < w; ++k) woff += wsum[k];
    int run = part[blockIdx.x] + woff + incl - s;
    #pragma unroll
    for (int j = 0; j < 8; ++j) {
        if (base + j < n) out[base + j] = run;
        run += e[j];
    }
    if (blockIdx.x == 0 && tid == 0) out[n] = part[nb];
}

// ---------------- weight prep ----------------

__global__ void k_wav(const float* __restrict__ W1, const float* __restrict__ b1,
                      const float* __restrict__ av1, float* __restrict__ wav,
                      float* __restrict__ bav) {
    int h = blockIdx.x;
    int k = threadIdx.x;
    float s = 0.f;
    for (int j = 0; j < DH; ++j) s += W1[(size_t)(h * DIN + k) * DH + j] * av1[h * DH + j];
    wav[h * DIN + k] = s;
    if (k == 0) {
        float t = 0.f;
        for (int j = 0; j < DH; ++j) t += b1[h * DH + j] * av1[h * DH + j];
        bav[h] = t;
    }
}

__global__ void k_build_wcatT(const float* __restrict__ W1, u16* __restrict__ WcatT) {
    int idx = blockIdx.x * 256 + threadIdx.x;
    if (idx >= 256 * DIN) return;
    int c = idx >> 7, k = idx & 127;
    int h = c >> 6, j = c & 63;
    WcatT[c * DIN + k] = f2bf(W1[((size_t)h * DIN + k) * DH + j]);
}

__global__ void k_build_w2T(const float* __restrict__ W2, u16* __restrict__ W2T) {
    int idx = blockIdx.x * 256 + threadIdx.x;
    if (idx >= 48 * DCAT) return;
    int c = idx >> 9, k = idx & 511;
    float v = (c < NC) ? W2[(size_t)k * NC + c] : 0.f;
    W2T[c * DCAT + k] = f2bf(v);
}

// ---------------- conversion + node attention term (layer 1) ----------------
__global__ void k_conv(const float* __restrict__ X, const float* __restrict__ wav,
                       const float* __restrict__ bav, u16* __restrict__ Xb,
                       float* __restrict__ sv8, int xoff, int N) {
    int wave = (blockIdx.x * blockDim.x + threadIdx.x) >> 6;
    int lane = threadIdx.x & 63;
    if (wave >= N) return;
    float2 a = *(const float2*)(X + (size_t)wave * DIN + lane * 2);
    u16 b0 = f2bf(a.x), b1 = f2bf(a.y);
    *(u16*)(Xb + (size_t)wave * DIN + lane * 2 + 0) = b0;
    *(u16*)(Xb + (size_t)wave * DIN + lane * 2 + 1) = b1;
    float s[NH];
    #pragma unroll
    for (int h = 0; h < NH; ++h) {
        float2 wv = *(const float2*)(wav + h * DIN + lane * 2);
        float t = a.x * wv.x + a.y * wv.y;
        #pragma unroll
        for (int off = 32; off >= 1; off >>= 1) t += __shfl_xor(t, off);
        s[h] = t;
    }
    if (lane == 0) {
        *(float4*)(sv8 + (size_t)wave * 8 + xoff) =
            make_float4(s[0] + bav[0], s[1] + bav[1], s[2] + bav[2], s[3] + bav[3]);
    }
}

// ---------------- edge mean (bf16, D=128), both inputs fused, 4 rows/iter ----------------
__global__ void k_edge_mean1(const u16* __restrict__ Xb0, const u16* __restrict__ Xb1,
                             const int* __restrict__ start_e, const int* __restrict__ csr_e_v,
                             u16* __restrict__ Xbar0, u16* __restrict__ Xbar1, int E) {
    int wave = (blockIdx.x * blockDim.x + threadIdx.x) >> 6;
    int lane = threadIdx.x & 63;
    if (wave >= E) return;
    int s = start_e[wave], t = start_e[wave + 1];
    int q = lane >> 4, c = lane & 15;
    float a0[8], a1[8];
    #pragma unroll
    for (int j = 0; j < 8; ++j) { a0[j] = 0.f; a1[j] = 0.f; }
    for (int i = s + q; i < t; i += 4) {
        int v = csr_e_v[i];
        u16x8 y0 = *(const u16x8*)(Xb0 + (size_t)v * DIN + c * 8);
        u16x8 y1 = *(const u16x8*)(Xb1 + (size_t)v * DIN + c * 8);
        #pragma unroll
        for (int j = 0; j < 8; ++j) { a0[j] += bf2f(y0[j]); a1[j] += bf2f(y1[j]); }
    }
    #pragma unroll
    for (int j = 0; j < 8; ++j) {
        a0[j] += __shfl_xor(a0[j], 16);
        a0[j] += __shfl_xor(a0[j], 32);
        a1[j] += __shfl_xor(a1[j], 16);
        a1[j] += __shfl_xor(a1[j], 32);
    }
    int deg = t - s;
    float inv = 1.f / (float)(deg > 1 ? deg : 1);
    if (q == 0) {
        u16x8 r0, r1;
        #pragma unroll
        for (int j = 0; j < 8; ++j) { r0[j] = f2bf(a0[j] * inv); r1[j] = f2bf(a1[j] * inv); }
        *(u16x8*)(Xbar0 + (size_t)wave * DIN + c * 8) = r0;
        *(u16x8*)(Xbar1 + (size_t)wave * DIN + c * 8) = r1;
    }
}

// ---------------- MFMA GEMM with fused row-dot epilogue ----------------
// DOTMODE 0: none; 1: per-head dots (64-col heads) -> dout[row*8 + z*4 + head]
// DOTMODE 2: single dot over ncols -> dout[row]
template <int KDIM, int NTILES, int DOTMODE>
__global__ __launch_bounds__(256) void k_gemm_mfma(const u16* __restrict__ A0,
                                                   const u16* __restrict__ A1, int M,
                                                   const u16* __restrict__ Bt,
                                                   const float* __restrict__ bias,
                                                   u16* __restrict__ out0, u16* __restrict__ out1,
                                                   int ldo, int ncols,
                                                   const float* __restrict__ dvec,
                                                   float* __restrict__ dout) {
    constexpr int LDB = KDIM + 8;
    __shared__ u16 Bs[NTILES * 16 * LDB];
    const u16* A = blockIdx.z ? A1 : A0;
    u16* out = blockIdx.z ? out1 : out0;
    int tid = threadIdx.x;
    int colbase = blockIdx.y * NTILES * 16;
    const u16* Btblk = Bt + (size_t)colbase * KDIM;
    for (int idx = tid * 4; idx < NTILES * 16 * KDIM; idx += 256 * 4) {
        int c = idx / KDIM, k = idx % KDIM;
        *(u16x4*)&Bs[c * LDB + k] = *(const u16x4*)(Btblk + c * KDIM + k);
    }
    __syncthreads();
    int w = tid >> 6, lane = tid & 63;
    int r0 = blockIdx.x * 64 + w * 16;
    int arow = r0 + (lane & 15);
    bool avalid = arow < M;
    const u16* ap = A + (size_t)arow * KDIM + (lane >> 4) * 8;
    f32x4 acc[NTILES];
    #pragma unroll
    for (int nt = 0; nt < NTILES; ++nt) acc[nt] = (f32x4){0.f, 0.f, 0.f, 0.f};
    #pragma unroll
    for (int k0 = 0; k0 < KDIM; k0 += 32) {
        bf16x8 a = (bf16x8)(short)0;
        if (avalid) a = *(const bf16x8*)(ap + k0);
        #pragma unroll
        for (int nt = 0; nt < NTILES; ++nt) {
            bf16x8 b = *(const bf16x8*)&Bs[(nt * 16 + (lane & 15)) * LDB + k0 + (lane >> 4) * 8];
            acc[nt] = __builtin_amdgcn_mfma_f32_16x16x32_bf16(a, b, acc[nt], 0, 0, 0);
        }
    }
    #pragma unroll
    for (int j = 0; j < 4; ++j) {
        int row = r0 + (lane >> 4) * 4 + j;
        float pA = 0.f, pB = 0.f;
        #pragma unroll
        for (int nt = 0; nt < NTILES; ++nt) {
            int col = colbase + nt * 16 + (lane & 15);
            bool cok = col < ncols;
            float val = cok ? acc[nt][j] + bias[col] : 0.f;
            if (DOTMODE == 1) {
                float dv = dvec[col];
                if (nt < NTILES / 2) pA += val * dv; else pB += val * dv;
            } else if (DOTMODE == 2) {
                pA += cok ? val * dvec[col] : 0.f;
            }
            if (row < M && cok) out[(size_t)row * ldo + col] = f2bf(val);
        }
        if (DOTMODE) {
            pA += __shfl_xor(pA, 1);
            pA += __shfl_xor(pA, 2);
            pA += __shfl_xor(pA, 4);
            pA += __shfl_xor(pA, 8);
            if (DOTMODE == 1) {
                pB += __shfl_xor(pB, 1);
                pB += __shfl_xor(pB, 2);
                pB += __shfl_xor(pB, 4);
                pB += __shfl_xor(pB, 8);
            }
            if ((lane & 15) == 0 && row < M) {
                if (DOTMODE == 1) {
                    int hb = blockIdx.y * 2 + blockIdx.z * 4;
                    dout[(size_t)row * 8 + hb] = pA;
                    dout[(size_t)row * 8 + hb + 1] = pB;
                } else {
                    dout[row] = pA;
                }
            }
        }
    }
}

// ---------------- sliced node pass (layer 1) ----------------
// Ycat is [E,512] interleaved (col = z*256 + h*64 + j). gridDim.z = 8 slices of 64 cols;
// slice sl covers exactly one (input z = sl>>2, head h = sl&3), i.e. cols sl*64..sl*64+63,
// and z*4+h == sl indexes se8/sv8 directly. Dispatch order (x fastest, z slowest) means all
// concurrent waves gather from one 2.56 MB Ycat slice -> fits per-XCD L2.
__global__ void k_node_pass1(const u16* __restrict__ Ycat, const float* __restrict__ se8,
                             const float* __restrict__ sv8, const int* __restrict__ start_v,
                             const int* __restrict__ csr_v_e, u16* __restrict__ hbuf, int N) {
    int wave = (blockIdx.x * blockDim.x + threadIdx.x) >> 6;
    int lane = threadIdx.x & 63;
    if (wave >= N) return;
    int sl = blockIdx.z;          // 0..7
    int p0 = start_v[wave], p1 = start_v[wave + 1];
    int g = lane >> 4;            // 4 pair-groups
    int c = lane & 15;            // 4 cols each
    u16* orow = hbuf + (size_t)wave * DCAT + sl * 64 + c * 4;
    if (p1 == p0) {
        if (g == 0) *(u16x4*)orow = (u16x4){0, 0, 0, 0};
        return;
    }
    float sv = sv8[(size_t)wave * 8 + sl];
    const u16* ybase = Ycat + sl * 64 + c * 4;
    float den = 0.f, a0 = 0.f, a1 = 0.f, a2 = 0.f, a3 = 0.f;
    for (int i = p0 + g; i < p1; i += 4) {
        int e = csr_v_e[i];
        float x = se8[e * 8 + sl] + sv;
        x = x >= 0.f ? x : 0.2f * x;
        float ex = __expf(x);
        den += ex;
        u16x4 y = *(const u16x4*)(ybase + (size_t)e * DCAT);
        a0 += ex * bf2f(y.x);
        a1 += ex * bf2f(y.y);
        a2 += ex * bf2f(y.z);
        a3 += ex * bf2f(y.w);
    }
    den += __shfl_xor(den, 16);
    den += __shfl_xor(den, 32);
    a0 += __shfl_xor(a0, 16); a0 += __shfl_xor(a0, 32);
    a1 += __shfl_xor(a1, 16); a1 += __shfl_xor(a1, 32);
    a2 += __shfl_xor(a2, 16); a2 += __shfl_xor(a2, 32);
    a3 += __shfl_xor(a3, 16); a3 += __shfl_xor(a3, 32);
    if (g == 0) {
        float inv = 1.f / den;
        float o0 = a0 * inv, o1 = a1 * inv, o2 = a2 * inv, o3 = a3 * inv;
        o0 = o0 > 0.f ? o0 : __expf(o0) - 1.f;
        o1 = o1 > 0.f ? o1 : __expf(o1) - 1.f;
        o2 = o2 > 0.f ? o2 : __expf(o2) - 1.f;
        o3 = o3 > 0.f ? o3 : __expf(o3) - 1.f;
        *(u16x4*)orow = (u16x4){f2bf(o0), f2bf(o1), f2bf(o2), f2bf(o3)};
    }
}

// ---------------- layer 2 small kernels ----------------

__global__ void k_edge_mean2(const u16* __restrict__ Xp2b, const int* __restrict__ start_e,
                             const int* __restrict__ csr_e_v, u16* __restrict__ Y2b,
                             const float* __restrict__ ae2, float* __restrict__ se2, int E) {
    int wave = (blockIdx.x * blockDim.x + threadIdx.x) >> 6;
    int lane = threadIdx.x & 63;
    if (wave >= E) return;
    int s = start_e[wave], t = start_e[wave + 1];
    int g = lane >> 4, c = lane & 15;
    bool act = c < 10;
    float acc[4];
    #pragma unroll
    for (int j = 0; j < 4; ++j) acc[j] = 0.f;
    for (int i = s + g; i < t; i += 4) {
        int v = csr_e_v[i];
        if (act) {
            u16x4 y = *(const u16x4*)(Xp2b + (size_t)v * NC + c * 4);
            acc[0] += bf2f(y.x);
            acc[1] += bf2f(y.y);
            acc[2] += bf2f(y.z);
            acc[3] += bf2f(y.w);
        }
    }
    #pragma unroll
    for (int j = 0; j < 4; ++j) {
        acc[j] += __shfl_xor(acc[j], 16);
        acc[j] += __shfl_xor(acc[j], 32);
    }
    int deg = t - s;
    float inv = 1.f / (float)(deg > 1 ? deg : 1);
    float p = 0.f;
    if (act) {
        float4 ae = *(const float4*)(ae2 + c * 4);
        float y0 = acc[0] * inv, y1 = acc[1] * inv, y2 = acc[2] * inv, y3 = acc[3] * inv;
        p = y0 * ae.x + y1 * ae.y + y2 * ae.z + y3 * ae.w;
        if (g == 0) {
            u16x4 r = {f2bf(y0), f2bf(y1), f2bf(y2), f2bf(y3)};
            *(u16x4*)(Y2b + (size_t)wave * NC + c * 4) = r;
        }
    }
    #pragma unroll
    for (int off = 8; off >= 1; off >>= 1) p += __shfl_xor(p, off);
    if (lane == 0) se2[wave] = p;
}

__global__ void k_node_pass2(const u16* __restrict__ Y2b, const float* __restrict__ se2,
                             const float* __restrict__ sv2, const int* __restrict__ start_v,
                             const int* __restrict__ csr_v_e, float* __restrict__ out, int N) {
    int wave = (blockIdx.x * blockDim.x + threadIdx.x) >> 6;
    int lane = threadIdx.x & 63;
    if (wave >= N) return;
    int s = start_v[wave], t = start_v[wave + 1];
    int g = lane >> 4, c = lane & 15;
    bool act = c < 10;
    float* orow = out + (size_t)wave * NC;
    if (t == s) {
        if (g == 0 && act) *(float4*)(orow + c * 4) = make_float4(0.f, 0.f, 0.f, 0.f);
        return;
    }
    float svv = sv2[wave];
    float den = 0.f;
    float acc[4];
    #pragma unroll
    for (int j = 0; j < 4; ++j) acc[j] = 0.f;
    for (int i = s + g; i < t; i += 4) {
        int e = csr_v_e[i];
        float x = se2[e] + svv;
        x = x >= 0.f ? x : 0.2f * x;
        float ex = __expf(x);
        den += ex;
        if (act) {
            u16x4 y = *(const u16x4*)(Y2b + (size_t)e * NC + c * 4);
            acc[0] += ex * bf2f(y.x);
            acc[1] += ex * bf2f(y.y);
            acc[2] += ex * bf2f(y.z);
            acc[3] += ex * bf2f(y.w);
        }
    }
    den += __shfl_xor(den, 16);
    den += __shfl_xor(den, 32);
    #pragma unroll
    for (int j = 0; j < 4; ++j) {
        acc[j] += __shfl_xor(acc[j], 16);
        acc[j] += __shfl_xor(acc[j], 32);
    }
    if (g == 0 && act) {
        float inv = 1.f / den;
        float4 o;
        float* op = &o.x;
        #pragma unroll
        for (int j = 0; j < 4; ++j) {
            float v = acc[j] * inv;
            op[j] = v > 0.f ? v : __expf(v) - 1.f;
        }
        *(float4*)(orow + c * 4) = o;
    }
}

// ---------------- launcher ----------------
extern "C" void kernel_launch(void* const* d_in, const int* in_sizes, int n_in,
                              void* d_out, int out_size, void* d_ws, size_t ws_size,
                              hipStream_t stream) {
    const float* x0 = (const float*)d_in[0];
    const float* x1 = (const float*)d_in[1];
    const float* W1 = (const float*)d_in[2];
    const float* b1 = (const float*)d_in[3];
    const float* ae1 = (const float*)d_in[4];
    const float* av1 = (const float*)d_in[5];
    const float* W2 = (const float*)d_in[6];
    const float* b2 = (const float*)d_in[7];
    const float* ae2 = (const float*)d_in[8];
    const float* av2 = (const float*)d_in[9];
    const int* pe = (const int*)d_in[10];
    const int* pv = (const int*)d_in[11];

    const int N = in_sizes[0] / DIN;  // 100000
    const int P = in_sizes[10];       // 1600000
    const int E = E_CONST;            // 20000

    char* base = (char*)d_ws;
    auto alloc = [&](size_t bytes) -> void* {
        void* p = (void*)base;
        base += (bytes + 255) & ~(size_t)255;
        return p;
    };
    u16* Xb0 = (u16*)alloc((size_t)N * DIN * 2);
    u16* Xb1 = (u16*)alloc((size_t)N * DIN * 2);
    u16* hbuf = (u16*)alloc((size_t)N * DCAT * 2);
    u16* Xbar0 = (u16*)alloc((size_t)E * DIN * 2);
    u16* Xbar1 = (u16*)alloc((size_t)E * DIN * 2);
    u16* Ycat = (u16*)alloc((size_t)E * 512 * 2);   // interleaved [E,512]
    u16* Xp2b = (u16*)alloc((size_t)N * NC * 2);
    u16* Y2b = (u16*)alloc((size_t)E * NC * 2);
    float* se8 = (float*)alloc((size_t)E * 8 * 4);
    float* se2 = (float*)alloc((size_t)E * 4);
    float* sv8 = (float*)alloc((size_t)N * 8 * 4);
    float* sv2 = (float*)alloc((size_t)N * 4);
    float* wav = (float*)alloc((size_t)NH * DIN * 4);
    float* bav = (float*)alloc((size_t)NH * 4);
    u16* WcatT = (u16*)alloc((size_t)256 * DIN * 2);
    u16* W2T = (u16*)alloc((size_t)48 * DCAT * 2);
    int* part = (int*)alloc((size_t)65 * 4);
    char* zstart = base;
    int* deg_e = (int*)alloc((size_t)E * 4);
    int* deg_v = (int*)alloc((size_t)N * 4);
    int* cur_e = (int*)alloc((size_t)E * 4);
    int* cur_v = (int*)alloc((size_t)N * 4);
    size_t zbytes = (size_t)(base - zstart);
    int* start_e = (int*)alloc((size_t)(E + 1) * 4);
    int* start_v = (int*)alloc((size_t)(N + 1) * 4);
    int* csr_e_v = (int*)alloc((size_t)P * 4);
    int* csr_v_e = (int*)alloc((size_t)P * 4);

    if ((size_t)(base - (char*)d_ws) > ws_size) return;

    hipMemsetAsync(zstart, 0, zbytes, stream);

    dim3 b256(256);
    int nch = (P + BIN_CHUNK - 1) / BIN_CHUNK;
    k_count_binned<<<nch * NXCD, b256, 0, stream>>>(pe, pv, deg_e, deg_v, P, E, N);
    int nbE = (E + SCAN_CHUNK - 1) / SCAN_CHUNK;   // 10
    int nbN = (N + SCAN_CHUNK - 1) / SCAN_CHUNK;   // 49
    k_scan1<<<nbE, b256, 0, stream>>>(deg_e, part, E);
    k_scan2<<<1, 64, 0, stream>>>(part, nbE);
    k_scan3<<<nbE, b256, 0, stream>>>(deg_e, part, start_e, E, nbE);
    k_scan1<<<nbN, b256, 0, stream>>>(deg_v, part, N);
    k_scan2<<<1, 64, 0, stream>>>(part, nbN);
    k_scan3<<<nbN, b256, 0, stream>>>(deg_v, part, start_v, N, nbN);
    k_scatter_binned<<<nch * NXCD, b256, 0, stream>>>(pe, pv, start_e, start_v, cur_e, cur_v,
                                                      csr_e_v, csr_v_e, P, E, N);

    k_wav<<<NH, DIN, 0, stream>>>(W1, b1, av1, wav, bav);
    k_build_wcatT<<<(256 * DIN + 255) / 256, b256, 0, stream>>>(W1, WcatT);
    k_build_w2T<<<(48 * DCAT + 255) / 256, b256, 0, stream>>>(W2, W2T);

    int gN4 = (N + 3) / 4;
    int gE4 = (E + 3) / 4;
    k_conv<<<gN4, b256, 0, stream>>>(x0, wav, bav, Xb0, sv8, 0, N);
    k_conv<<<gN4, b256, 0, stream>>>(x1, wav, bav, Xb1, sv8, 4, N);

    k_edge_mean1<<<gE4, b256, 0, stream>>>(Xb0, Xb1, start_e, csr_e_v, Xbar0, Xbar1, E);
    dim3 g1((E + 63) / 64, 2, 2);
    k_gemm_mfma<DIN, 8, 1><<<g1, b256, 0, stream>>>(Xbar0, Xbar1, E, WcatT, b1,
                                                    Ycat, Ycat + 256, 512, 256, ae1, se8);
    dim3 gnp(gN4, 1, 8);
    k_node_pass1<<<gnp, b256, 0, stream>>>(Ycat, se8, sv8, start_v, csr_v_e, hbuf, N);

    dim3 g2((N + 63) / 64, 1, 1);
    k_gemm_mfma<DCAT, 3, 2><<<g2, b256, 0, stream>>>(hbuf, hbuf, N, W2T, b2, Xp2b, Xp2b,
                                                     NC, NC, av2, sv2);
    k_edge_mean2<<<gE4, b256, 0, stream>>>(Xp2b, start_e, csr_e_v, Y2b, ae2, se2, E);
    k_node_pass2<<<gN4, b256, 0, stream>>>(Y2b, se2, sv2, start_v, csr_v_e, (float*)d_out, N);
}

// Round 7
// 881.975 us; speedup vs baseline: 1.2174x; 1.2174x over previous
//
#include <hip/hip_runtime.h>
#include <cstdint>
#include <cstddef>

// N=100000, E=20000, P=1600000, din=128, dh=64, H=4, DCAT=512, C=40
static constexpr int DIN = 128;
static constexpr int DH = 64;
static constexpr int NH = 4;
static constexpr int DCAT = 512;
static constexpr int NC = 40;
static constexpr int E_CONST = 20000;
static constexpr int SCAN_CHUNK = 2048;
static constexpr int NXCD = 8;
static constexpr int BIN_CHUNK = 8192;

typedef unsigned short u16;
typedef __attribute__((ext_vector_type(4))) unsigned short u16x4;
typedef __attribute__((ext_vector_type(8))) unsigned short u16x8;
typedef __attribute__((ext_vector_type(8))) short bf16x8;
typedef __attribute__((ext_vector_type(4))) float f32x4;

static __device__ __forceinline__ float bf2f(u16 u) {
    union { unsigned int i; float f; } x;
    x.i = ((unsigned int)u) << 16;
    return x.f;
}
static __device__ __forceinline__ u16 f2bf(float f) {
    union { float f; unsigned int i; } x;
    x.f = f;
    unsigned int r = x.i + 0x7fffu + ((x.i >> 16) & 1u);
    return (u16)(r >> 16);
}

// ---------------- CSR build (XCD-binned) ----------------

__global__ void k_count_binned(const int* __restrict__ pe, const int* __restrict__ pv,
                               int* __restrict__ deg_e, int* __restrict__ deg_v,
                               int P, int E, int N) {
    int g = blockIdx.x & 7;
    int chunk = blockIdx.x >> 3;
    int lo_e = g * E / NXCD, hi_e = (g + 1) * E / NXCD;
    int lo_v = g * N / NXCD, hi_v = (g + 1) * N / NXCD;
    int p0 = chunk * BIN_CHUNK;
    int p1 = p0 + BIN_CHUNK < P ? p0 + BIN_CHUNK : P;
    for (int p = p0 + threadIdx.x; p < p1; p += 256) {
        int e = pe[p];
        if (e >= lo_e && e < hi_e) atomicAdd(&deg_e[e], 1);
        int v = pv[p];
        if (v >= lo_v && v < hi_v) atomicAdd(&deg_v[v], 1);
    }
}

__global__ void k_scatter_binned(const int* __restrict__ pe, const int* __restrict__ pv,
                                 const int* __restrict__ start_e, const int* __restrict__ start_v,
                                 int* __restrict__ cur_e, int* __restrict__ cur_v,
                                 int* __restrict__ csr_e_v, int* __restrict__ csr_v_e,
                                 int P, int E, int N) {
    int g = blockIdx.x & 7;
    int chunk = blockIdx.x >> 3;
    int lo_e = g * E / NXCD, hi_e = (g + 1) * E / NXCD;
    int lo_v = g * N / NXCD, hi_v = (g + 1) * N / NXCD;
    int p0 = chunk * BIN_CHUNK;
    int p1 = p0 + BIN_CHUNK < P ? p0 + BIN_CHUNK : P;
    for (int p = p0 + threadIdx.x; p < p1; p += 256) {
        int e = pe[p];
        int v = pv[p];
        if (e >= lo_e && e < hi_e) {
            int ie = atomicAdd(&cur_e[e], 1);
            csr_e_v[start_e[e] + ie] = v;
        }
        if (v >= lo_v && v < hi_v) {
            int iv = atomicAdd(&cur_v[v], 1);
            csr_v_e[start_v[v] + iv] = e;
        }
    }
}

// multi-block scan: phase 1 — per-block sums
__global__ void k_scan1(const int* __restrict__ in, int* __restrict__ part, int n) {
    __shared__ int wsum[4];
    int tid = threadIdx.x, lane = tid & 63, w = tid >> 6;
    int base = blockIdx.x * SCAN_CHUNK + tid * 8;
    int s = 0;
    #pragma unroll
    for (int j = 0; j < 8; ++j)
        if (base + j < n) s += in[base + j];
    #pragma unroll
    for (int off = 32; off >= 1; off >>= 1) s += __shfl_xor(s, off);
    if (lane == 0) wsum[w] = s;
    __syncthreads();
    if (tid == 0) part[blockIdx.x] = wsum[0] + wsum[1] + wsum[2] + wsum[3];
}

// phase 2 — single wave exclusive scan of partials (nb <= 64), part[nb]=total
__global__ void k_scan2(int* __restrict__ part, int nb) {
    int tid = threadIdx.x;
    int v = (tid < nb) ? part[tid] : 0;
    int incl = v;
    #pragma unroll
    for (int off = 1; off < 64; off <<= 1) {
        int t = __shfl_up(incl, off);
        if (tid >= off) incl += t;
    }
    if (tid < nb) part[tid] = incl - v;
    if (tid == 63) part[nb] = incl;
}

// phase 3 — rescan each chunk, add block offset
__global__ void k_scan3(const int* __restrict__ in, const int* __restrict__ part,
                        int* __restrict__ out, int n, int nb) {
    __shared__ int wsum[4];
    int tid = threadIdx.x, lane = tid & 63, w = tid >> 6;
    int base = blockIdx.x * SCAN_CHUNK + tid * 8;
    int e[8];
    int s = 0;
    #pragma unroll
    for (int j = 0; j < 8; ++j) {
        e[j] = (base + j < n) ? in[base + j] : 0;
        s += e[j];
    }
    int incl = s;
    #pragma unroll
    for (int off = 1; off < 64; off <<= 1) {
        int t = __shfl_up(incl, off);
        if (lane >= off) incl += t;
    }
    if (lane == 63) wsum[w] = incl;
    __syncthreads();
    int woff = 0;
    for (int k = 0; k < w; ++k) woff += wsum[k];
    int run = part[blockIdx.x] + woff + incl - s;
    #pragma unroll
    for (int j = 0; j < 8; ++j) {
        if (base + j < n) out[base + j] = run;
        run += e[j];
    }
    if (blockIdx.x == 0 && tid == 0) out[n] = part[nb];
}

// ---------------- weight prep ----------------

__global__ void k_wav(const float* __restrict__ W1, const float* __restrict__ b1,
                      const float* __restrict__ av1, float* __restrict__ wav,
                      float* __restrict__ bav) {
    int h = blockIdx.x;
    int k = threadIdx.x;
    float s = 0.f;
    for (int j = 0; j < DH; ++j) s += W1[(size_t)(h * DIN + k) * DH + j] * av1[h * DH + j];
    wav[h * DIN + k] = s;
    if (k == 0) {
        float t = 0.f;
        for (int j = 0; j < DH; ++j) t += b1[h * DH + j] * av1[h * DH + j];
        bav[h] = t;
    }
}

__global__ void k_build_wcatT(const float* __restrict__ W1, u16* __restrict__ WcatT) {
    int idx = blockIdx.x * 256 + threadIdx.x;
    if (idx >= 256 * DIN) return;
    int c = idx >> 7, k = idx & 127;
    int h = c >> 6, j = c & 63;
    WcatT[c * DIN + k] = f2bf(W1[((size_t)h * DIN + k) * DH + j]);
}

__global__ void k_build_w2T(const float* __restrict__ W2, u16* __restrict__ W2T) {
    int idx = blockIdx.x * 256 + threadIdx.x;
    if (idx >= 48 * DCAT) return;
    int c = idx >> 9, k = idx & 511;
    float v = (c < NC) ? W2[(size_t)k * NC + c] : 0.f;
    W2T[c * DCAT + k] = f2bf(v);
}

// ---------------- conversion + node attention term (layer 1) ----------------
// Xbi interleaved [N][2][128]; sv8[n*8 + h*2 + z]
__global__ void k_conv(const float* __restrict__ X, const float* __restrict__ wav,
                       const float* __restrict__ bav, u16* __restrict__ Xbi,
                       float* __restrict__ sv8, int xz, int N) {
    int wave = (blockIdx.x * blockDim.x + threadIdx.x) >> 6;
    int lane = threadIdx.x & 63;
    if (wave >= N) return;
    float2 a = *(const float2*)(X + (size_t)wave * DIN + lane * 2);
    unsigned int packed = (unsigned int)f2bf(a.x) | ((unsigned int)f2bf(a.y) << 16);
    *(unsigned int*)(Xbi + (size_t)wave * 256 + xz * 128 + lane * 2) = packed;
    float s[NH];
    #pragma unroll
    for (int h = 0; h < NH; ++h) {
        float2 wv = *(const float2*)(wav + h * DIN + lane * 2);
        float t = a.x * wv.x + a.y * wv.y;
        #pragma unroll
        for (int off = 32; off >= 1; off >>= 1) t += __shfl_xor(t, off);
        s[h] = t;
    }
    if (lane == 0) {
        #pragma unroll
        for (int h = 0; h < NH; ++h) sv8[(size_t)wave * 8 + h * 2 + xz] = s[h] + bav[h];
    }
}

// ---------------- edge mean (bf16, D=128), both inputs, unroll-3 pipelined ----------------
__global__ void k_edge_mean1(const u16* __restrict__ Xbi, const int* __restrict__ start_e,
                             const int* __restrict__ csr_e_v, u16* __restrict__ Xbar0,
                             u16* __restrict__ Xbar1, int E) {
    int wave = (blockIdx.x * blockDim.x + threadIdx.x) >> 6;
    int lane = threadIdx.x & 63;
    if (wave >= E) return;
    int s = start_e[wave], t = start_e[wave + 1];
    int q = lane >> 4, c = lane & 15;
    float a0[8], a1[8];
    #pragma unroll
    for (int j = 0; j < 8; ++j) { a0[j] = 0.f; a1[j] = 0.f; }
    int i = s + q;
    u16x8 y0A = {0}, y1A = {0}, y0B = {0}, y1B = {0}, y0C = {0}, y1C = {0};
#define EM1_LOAD(Y0, Y1, IDX) { int v_ = csr_e_v[IDX]; \
        const u16* yp_ = Xbi + (size_t)v_ * 256 + c * 8; \
        Y0 = *(const u16x8*)yp_; Y1 = *(const u16x8*)(yp_ + 128); }
#define EM1_CONSUME(Y0, Y1) { \
        _Pragma("unroll") \
        for (int j = 0; j < 8; ++j) { a0[j] += bf2f(Y0[j]); a1[j] += bf2f(Y1[j]); } }
    if (i < t) EM1_LOAD(y0A, y1A, i);
    if (i + 4 < t) EM1_LOAD(y0B, y1B, i + 4);
    if (i + 8 < t) EM1_LOAD(y0C, y1C, i + 8);
    for (; i + 8 < t; i += 12) {
        EM1_CONSUME(y0A, y1A);
        if (i + 12 < t) EM1_LOAD(y0A, y1A, i + 12);
        EM1_CONSUME(y0B, y1B);
        if (i + 16 < t) EM1_LOAD(y0B, y1B, i + 16);
        EM1_CONSUME(y0C, y1C);
        if (i + 20 < t) EM1_LOAD(y0C, y1C, i + 20);
    }
    if (i < t) EM1_CONSUME(y0A, y1A);
    if (i + 4 < t) EM1_CONSUME(y0B, y1B);
#undef EM1_LOAD
#undef EM1_CONSUME
    #pragma unroll
    for (int j = 0; j < 8; ++j) {
        a0[j] += __shfl_xor(a0[j], 16);
        a0[j] += __shfl_xor(a0[j], 32);
        a1[j] += __shfl_xor(a1[j], 16);
        a1[j] += __shfl_xor(a1[j], 32);
    }
    int deg = t - s;
    float inv = 1.f / (float)(deg > 1 ? deg : 1);
    if (q == 0) {
        u16x8 r0, r1;
        #pragma unroll
        for (int j = 0; j < 8; ++j) { r0[j] = f2bf(a0[j] * inv); r1[j] = f2bf(a1[j] * inv); }
        *(u16x8*)(Xbar0 + (size_t)wave * DIN + c * 8) = r0;
        *(u16x8*)(Xbar1 + (size_t)wave * DIN + c * 8) = r1;
    }
}

// ---------------- MFMA GEMM with fused row-dot epilogue ----------------
// DOTMODE 0: none; 1: per-head dots -> dout[row*8 + head*2 + z]; 2: single dot -> dout[row]
template <int KDIM, int NTILES, int DOTMODE>
__global__ __launch_bounds__(256) void k_gemm_mfma(const u16* __restrict__ A0,
                                                   const u16* __restrict__ A1, int M,
                                                   const u16* __restrict__ Bt,
                                                   const float* __restrict__ bias,
                                                   u16* __restrict__ out0, u16* __restrict__ out1,
                                                   int ldo, int ncols,
                                                   const float* __restrict__ dvec,
                                                   float* __restrict__ dout) {
    constexpr int LDB = KDIM + 8;
    __shared__ u16 Bs[NTILES * 16 * LDB];
    const u16* A = blockIdx.z ? A1 : A0;
    u16* out = blockIdx.z ? out1 : out0;
    int tid = threadIdx.x;
    int colbase = blockIdx.y * NTILES * 16;
    const u16* Btblk = Bt + (size_t)colbase * KDIM;
    for (int idx = tid * 4; idx < NTILES * 16 * KDIM; idx += 256 * 4) {
        int c = idx / KDIM, k = idx % KDIM;
        *(u16x4*)&Bs[c * LDB + k] = *(const u16x4*)(Btblk + c * KDIM + k);
    }
    __syncthreads();
    int w = tid >> 6, lane = tid & 63;
    int r0 = blockIdx.x * 64 + w * 16;
    int arow = r0 + (lane & 15);
    bool avalid = arow < M;
    const u16* ap = A + (size_t)arow * KDIM + (lane >> 4) * 8;
    f32x4 acc[NTILES];
    #pragma unroll
    for (int nt = 0; nt < NTILES; ++nt) acc[nt] = (f32x4){0.f, 0.f, 0.f, 0.f};
    #pragma unroll
    for (int k0 = 0; k0 < KDIM; k0 += 32) {
        bf16x8 a = (bf16x8)(short)0;
        if (avalid) a = *(const bf16x8*)(ap + k0);
        #pragma unroll
        for (int nt = 0; nt < NTILES; ++nt) {
            bf16x8 b = *(const bf16x8*)&Bs[(nt * 16 + (lane & 15)) * LDB + k0 + (lane >> 4) * 8];
            acc[nt] = __builtin_amdgcn_mfma_f32_16x16x32_bf16(a, b, acc[nt], 0, 0, 0);
        }
    }
    #pragma unroll
    for (int j = 0; j < 4; ++j) {
        int row = r0 + (lane >> 4) * 4 + j;
        float pA = 0.f, pB = 0.f;
        #pragma unroll
        for (int nt = 0; nt < NTILES; ++nt) {
            int col = colbase + nt * 16 + (lane & 15);
            bool cok = col < ncols;
            float val = cok ? acc[nt][j] + bias[col] : 0.f;
            if (DOTMODE == 1) {
                float dv = dvec[col];
                if (nt < NTILES / 2) pA += val * dv; else pB += val * dv;
            } else if (DOTMODE == 2) {
                pA += cok ? val * dvec[col] : 0.f;
            }
            if (row < M && cok) out[(size_t)row * ldo + col] = f2bf(val);
        }
        if (DOTMODE) {
            pA += __shfl_xor(pA, 1);
            pA += __shfl_xor(pA, 2);
            pA += __shfl_xor(pA, 4);
            pA += __shfl_xor(pA, 8);
            if (DOTMODE == 1) {
                pB += __shfl_xor(pB, 1);
                pB += __shfl_xor(pB, 2);
                pB += __shfl_xor(pB, 4);
                pB += __shfl_xor(pB, 8);
            }
            if ((lane & 15) == 0 && row < M) {
                if (DOTMODE == 1) {
                    int hbase = blockIdx.y * 2;   // head of pA; pB = hbase+1
                    int z = blockIdx.z;
                    dout[(size_t)row * 8 + hbase * 2 + z] = pA;
                    dout[(size_t)row * 8 + (hbase + 1) * 2 + z] = pB;
                } else {
                    dout[row] = pA;
                }
            }
        }
    }
}

// ---------------- fused node pass (layer 1), both inputs, unroll-3 pipelined ----------------
// Ycat interleaved [E,512] (input z at cols z*256). se8[e*8+h*2+z], sv8 likewise.
// No-max softmax: scores bounded (weights*0.05, unit-normal X) -> exp safe in f32.
__global__ void k_node_pass1(const u16* __restrict__ Ycat, const float* __restrict__ se8,
                             const float* __restrict__ sv8, const int* __restrict__ start_v,
                             const int* __restrict__ csr_v_e, u16* __restrict__ hbuf, int N) {
    int wave = (blockIdx.x * blockDim.x + threadIdx.x) >> 6;
    int lane = threadIdx.x & 63;
    if (wave >= N) return;
    int p0 = start_v[wave], p1 = start_v[wave + 1];
    int g = lane >> 5;   // 2 pair groups
    int c = lane & 31;   // 8 cols per input each
    int h = c >> 3;      // head
    u16* orow = hbuf + (size_t)wave * DCAT + c * 8;
    if (p1 == p0) {
        if (g == 0) {
            u16x8 z8 = {0, 0, 0, 0, 0, 0, 0, 0};
            *(u16x8*)orow = z8;
            *(u16x8*)(orow + 256) = z8;
        }
        return;
    }
    float sv0 = sv8[(size_t)wave * 8 + h * 2];
    float sv1 = sv8[(size_t)wave * 8 + h * 2 + 1];
    float den0 = 0.f, den1 = 0.f;
    float a0[8], a1[8];
    #pragma unroll
    for (int j = 0; j < 8; ++j) { a0[j] = 0.f; a1[j] = 0.f; }
    int i = p0 + g;
    float2 sA = {0.f, 0.f}, sB = {0.f, 0.f}, sC = {0.f, 0.f};
    u16x8 q0A = {0}, q1A = {0}, q0B = {0}, q1B = {0}, q0C = {0}, q1C = {0};
#define NP1_LOAD(S, Q0, Q1, IDX) { int e_ = csr_v_e[IDX]; \
        S = *(const float2*)(se8 + e_ * 8 + h * 2); \
        const u16* yp_ = Ycat + (size_t)e_ * 512 + c * 8; \
        Q0 = *(const u16x8*)yp_; Q1 = *(const u16x8*)(yp_ + 256); }
#define NP1_CONSUME(S, Q0, Q1) { \
        float x0_ = S.x + sv0; x0_ = fmaxf(x0_, 0.2f * x0_); float ex0_ = __expf(x0_); \
        float x1_ = S.y + sv1; x1_ = fmaxf(x1_, 0.2f * x1_); float ex1_ = __expf(x1_); \
        den0 += ex0_; den1 += ex1_; \
        _Pragma("unroll") \
        for (int j = 0; j < 8; ++j) { a0[j] += ex0_ * bf2f(Q0[j]); a1[j] += ex1_ * bf2f(Q1[j]); } }
    if (i < p1) NP1_LOAD(sA, q0A, q1A, i);
    if (i + 2 < p1) NP1_LOAD(sB, q0B, q1B, i + 2);
    if (i + 4 < p1) NP1_LOAD(sC, q0C, q1C, i + 4);
    for (; i + 4 < p1; i += 6) {
        NP1_CONSUME(sA, q0A, q1A);
        if (i + 6 < p1) NP1_LOAD(sA, q0A, q1A, i + 6);
        NP1_CONSUME(sB, q0B, q1B);
        if (i + 8 < p1) NP1_LOAD(sB, q0B, q1B, i + 8);
        NP1_CONSUME(sC, q0C, q1C);
        if (i + 10 < p1) NP1_LOAD(sC, q0C, q1C, i + 10);
    }
    if (i < p1) NP1_CONSUME(sA, q0A, q1A);
    if (i + 2 < p1) NP1_CONSUME(sB, q0B, q1B);
#undef NP1_LOAD
#undef NP1_CONSUME
    den0 += __shfl_xor(den0, 32);
    den1 += __shfl_xor(den1, 32);
    #pragma unroll
    for (int j = 0; j < 8; ++j) {
        a0[j] += __shfl_xor(a0[j], 32);
        a1[j] += __shfl_xor(a1[j], 32);
    }
    float i0 = 1.f / den0, i1 = 1.f / den1;
    u16x8 r0, r1;
    #pragma unroll
    for (int j = 0; j < 8; ++j) {
        float o0 = a0[j] * i0;
        float o1 = a1[j] * i1;
        o0 = o0 > 0.f ? o0 : __expf(o0) - 1.f;
        o1 = o1 > 0.f ? o1 : __expf(o1) - 1.f;
        r0[j] = f2bf(o0);
        r1[j] = f2bf(o1);
    }
    if (g == 0) {
        *(u16x8*)orow = r0;
        *(u16x8*)(orow + 256) = r1;
    }
}

// ---------------- layer 2 small kernels ----------------

__global__ void k_edge_mean2(const u16* __restrict__ Xp2b, const int* __restrict__ start_e,
                             const int* __restrict__ csr_e_v, u16* __restrict__ Y2b,
                             const float* __restrict__ ae2, float* __restrict__ se2, int E) {
    int wave = (blockIdx.x * blockDim.x + threadIdx.x) >> 6;
    int lane = threadIdx.x & 63;
    if (wave >= E) return;
    int s = start_e[wave], t = start_e[wave + 1];
    int g = lane >> 4, c = lane & 15;
    bool act = c < 10;
    float acc[4];
    #pragma unroll
    for (int j = 0; j < 4; ++j) acc[j] = 0.f;
    for (int i = s + g; i < t; i += 4) {
        int v = csr_e_v[i];
        if (act) {
            u16x4 y = *(const u16x4*)(Xp2b + (size_t)v * NC + c * 4);
            acc[0] += bf2f(y.x);
            acc[1] += bf2f(y.y);
            acc[2] += bf2f(y.z);
            acc[3] += bf2f(y.w);
        }
    }
    #pragma unroll
    for (int j = 0; j < 4; ++j) {
        acc[j] += __shfl_xor(acc[j], 16);
        acc[j] += __shfl_xor(acc[j], 32);
    }
    int deg = t - s;
    float inv = 1.f / (float)(deg > 1 ? deg : 1);
    float p = 0.f;
    if (act) {
        float4 ae = *(const float4*)(ae2 + c * 4);
        float y0 = acc[0] * inv, y1 = acc[1] * inv, y2 = acc[2] * inv, y3 = acc[3] * inv;
        p = y0 * ae.x + y1 * ae.y + y2 * ae.z + y3 * ae.w;
        if (g == 0) {
            u16x4 r = {f2bf(y0), f2bf(y1), f2bf(y2), f2bf(y3)};
            *(u16x4*)(Y2b + (size_t)wave * NC + c * 4) = r;
        }
    }
    #pragma unroll
    for (int off = 8; off >= 1; off >>= 1) p += __shfl_xor(p, off);
    if (lane == 0) se2[wave] = p;
}

__global__ void k_node_pass2(const u16* __restrict__ Y2b, const float* __restrict__ se2,
                             const float* __restrict__ sv2, const int* __restrict__ start_v,
                             const int* __restrict__ csr_v_e, float* __restrict__ out, int N) {
    int wave = (blockIdx.x * blockDim.x + threadIdx.x) >> 6;
    int lane = threadIdx.x & 63;
    if (wave >= N) return;
    int s = start_v[wave], t = start_v[wave + 1];
    int g = lane >> 4, c = lane & 15;
    bool act = c < 10;
    float* orow = out + (size_t)wave * NC;
    if (t == s) {
        if (g == 0 && act) *(float4*)(orow + c * 4) = make_float4(0.f, 0.f, 0.f, 0.f);
        return;
    }
    float svv = sv2[wave];
    float den = 0.f;
    float acc[4];
    #pragma unroll
    for (int j = 0; j < 4; ++j) acc[j] = 0.f;
    for (int i = s + g; i < t; i += 4) {
        int e = csr_v_e[i];
        float x = se2[e] + svv;
        x = fmaxf(x, 0.2f * x);
        float ex = __expf(x);
        den += ex;
        if (act) {
            u16x4 y = *(const u16x4*)(Y2b + (size_t)e * NC + c * 4);
            acc[0] += ex * bf2f(y.x);
            acc[1] += ex * bf2f(y.y);
            acc[2] += ex * bf2f(y.z);
            acc[3] += ex * bf2f(y.w);
        }
    }
    den += __shfl_xor(den, 16);
    den += __shfl_xor(den, 32);
    #pragma unroll
    for (int j = 0; j < 4; ++j) {
        acc[j] += __shfl_xor(acc[j], 16);
        acc[j] += __shfl_xor(acc[j], 32);
    }
    if (g == 0 && act) {
        float inv = 1.f / den;
        float4 o;
        float* op = &o.x;
        #pragma unroll
        for (int j = 0; j < 4; ++j) {
            float v = acc[j] * inv;
            op[j] = v > 0.f ? v : __expf(v) - 1.f;
        }
        *(float4*)(orow + c * 4) = o;
    }
}

// ---------------- launcher ----------------
extern "C" void kernel_launch(void* const* d_in, const int* in_sizes, int n_in,
                              void* d_out, int out_size, void* d_ws, size_t ws_size,
                              hipStream_t stream) {
    const float* x0 = (const float*)d_in[0];
    const float* x1 = (const float*)d_in[1];
    const float* W1 = (const float*)d_in[2];
    const float* b1 = (const float*)d_in[3];
    const float* ae1 = (const float*)d_in[4];
    const float* av1 = (const float*)d_in[5];
    const float* W2 = (const float*)d_in[6];
    const float* b2 = (const float*)d_in[7];
    const float* ae2 = (const float*)d_in[8];
    const float* av2 = (const float*)d_in[9];
    const int* pe = (const int*)d_in[10];
    const int* pv = (const int*)d_in[11];

    const int N = in_sizes[0] / DIN;  // 100000
    const int P = in_sizes[10];       // 1600000
    const int E = E_CONST;            // 20000

    char* base = (char*)d_ws;
    auto alloc = [&](size_t bytes) -> void* {
        void* p = (void*)base;
        base += (bytes + 255) & ~(size_t)255;
        return p;
    };
    u16* Xbi = (u16*)alloc((size_t)N * 256 * 2);    // interleaved [N][2][128]
    u16* hbuf = (u16*)alloc((size_t)N * DCAT * 2);
    u16* Xbar0 = (u16*)alloc((size_t)E * DIN * 2);
    u16* Xbar1 = (u16*)alloc((size_t)E * DIN * 2);
    u16* Ycat = (u16*)alloc((size_t)E * 512 * 2);   // interleaved [E,512]
    u16* Xp2b = (u16*)alloc((size_t)N * NC * 2);
    u16* Y2b = (u16*)alloc((size_t)E * NC * 2);
    float* se8 = (float*)alloc((size_t)E * 8 * 4);
    float* se2 = (float*)alloc((size_t)E * 4);
    float* sv8 = (float*)alloc((size_t)N * 8 * 4);
    float* sv2 = (float*)alloc((size_t)N * 4);
    float* wav = (float*)alloc((size_t)NH * DIN * 4);
    float* bav = (float*)alloc((size_t)NH * 4);
    u16* WcatT = (u16*)alloc((size_t)256 * DIN * 2);
    u16* W2T = (u16*)alloc((size_t)48 * DCAT * 2);
    int* part = (int*)alloc((size_t)65 * 4);
    char* zstart = base;
    int* deg_e = (int*)alloc((size_t)E * 4);
    int* deg_v = (int*)alloc((size_t)N * 4);
    int* cur_e = (int*)alloc((size_t)E * 4);
    int* cur_v = (int*)alloc((size_t)N * 4);
    size_t zbytes = (size_t)(base - zstart);
    int* start_e = (int*)alloc((size_t)(E + 1) * 4);
    int* start_v = (int*)alloc((size_t)(N + 1) * 4);
    int* csr_e_v = (int*)alloc((size_t)P * 4);
    int* csr_v_e = (int*)alloc((size_t)P * 4);

    if ((size_t)(base - (char*)d_ws) > ws_size) return;

    hipMemsetAsync(zstart, 0, zbytes, stream);

    dim3 b256(256);
    int nch = (P + BIN_CHUNK - 1) / BIN_CHUNK;
    k_count_binned<<<nch * NXCD, b256, 0, stream>>>(pe, pv, deg_e, deg_v, P, E, N);
    int nbE = (E + SCAN_CHUNK - 1) / SCAN_CHUNK;
    int nbN = (N + SCAN_CHUNK - 1) / SCAN_CHUNK;
    k_scan1<<<nbE, b256, 0, stream>>>(deg_e, part, E);
    k_scan2<<<1, 64, 0, stream>>>(part, nbE);
    k_scan3<<<nbE, b256, 0, stream>>>(deg_e, part, start_e, E, nbE);
    k_scan1<<<nbN, b256, 0, stream>>>(deg_v, part, N);
    k_scan2<<<1, 64, 0, stream>>>(part, nbN);
    k_scan3<<<nbN, b256, 0, stream>>>(deg_v, part, start_v, N, nbN);
    k_scatter_binned<<<nch * NXCD, b256, 0, stream>>>(pe, pv, start_e, start_v, cur_e, cur_v,
                                                      csr_e_v, csr_v_e, P, E, N);

    k_wav<<<NH, DIN, 0, stream>>>(W1, b1, av1, wav, bav);
    k_build_wcatT<<<(256 * DIN + 255) / 256, b256, 0, stream>>>(W1, WcatT);
    k_build_w2T<<<(48 * DCAT + 255) / 256, b256, 0, stream>>>(W2, W2T);

    int gN4 = (N + 3) / 4;
    int gE4 = (E + 3) / 4;
    k_conv<<<gN4, b256, 0, stream>>>(x0, wav, bav, Xbi, sv8, 0, N);
    k_conv<<<gN4, b256, 0, stream>>>(x1, wav, bav, Xbi, sv8, 1, N);

    k_edge_mean1<<<gE4, b256, 0, stream>>>(Xbi, start_e, csr_e_v, Xbar0, Xbar1, E);
    dim3 g1((E + 63) / 64, 2, 2);
    k_gemm_mfma<DIN, 8, 1><<<g1, b256, 0, stream>>>(Xbar0, Xbar1, E, WcatT, b1,
                                                    Ycat, Ycat + 256, 512, 256, ae1, se8);
    k_node_pass1<<<gN4, b256, 0, stream>>>(Ycat, se8, sv8, start_v, csr_v_e, hbuf, N);

    dim3 g2((N + 63) / 64, 1, 1);
    k_gemm_mfma<DCAT, 3, 2><<<g2, b256, 0, stream>>>(hbuf, hbuf, N, W2T, b2, Xp2b, Xp2b,
                                                     NC, NC, av2, sv2);
    k_edge_mean2<<<gE4, b256, 0, stream>>>(Xp2b, start_e, csr_e_v, Y2b, ae2, se2, E);
    k_node_pass2<<<gN4, b256, 0, stream>>>(Y2b, se2, sv2, start_v, csr_v_e, (float*)d_out, N);
}

// Round 8
// 675.427 us; speedup vs baseline: 1.5897x; 1.3058x over previous
//
#include <hip/hip_runtime.h>
#include <cstdint>
#include <cstddef>

// N=100000, E=20000, P=1600000, din=128, dh=64, H=4, DCAT=512, C=40
static constexpr int DIN = 128;
static constexpr int DH = 64;
static constexpr int NH = 4;
static constexpr int DCAT = 512;
static constexpr int NC = 40;
static constexpr int E_CONST = 20000;
// bucket sort: v-buckets of 512 nodes (196), e-buckets of 128 edges (157)
static constexpr int SH_V = 9, SUBD_V = 512;
static constexpr int SH_E = 7, SUBD_E = 128;
static constexpr int CHUNKA = 4096;   // pairs per scatter block

typedef unsigned short u16;
typedef __attribute__((ext_vector_type(4))) unsigned short u16x4;
typedef __attribute__((ext_vector_type(8))) unsigned short u16x8;
typedef __attribute__((ext_vector_type(8))) short bf16x8;
typedef __attribute__((ext_vector_type(4))) float f32x4;

static __device__ __forceinline__ float bf2f(u16 u) {
    union { unsigned int i; float f; } x;
    x.i = ((unsigned int)u) << 16;
    return x.f;
}
static __device__ __forceinline__ u16 f2bf(float f) {
    union { float f; unsigned int i; } x;
    x.f = f;
    unsigned int r = x.i + 0x7fffu + ((x.i >> 16) & 1u);
    return (u16)(r >> 16);
}

// ---------------- CSR build via 2-level bucket sort ----------------

// phase 0: dual LDS histogram -> global bucket totals (btot_v[196], btot_e[157])
__global__ void k_hist2(const int* __restrict__ pv, const int* __restrict__ pe,
                        int* __restrict__ btot_v, int* __restrict__ btot_e, int P) {
    __shared__ int cv[256], ce[256];
    int tid = threadIdx.x;
    cv[tid] = 0; ce[tid] = 0;
    __syncthreads();
    int p0 = blockIdx.x * CHUNKA;
    #pragma unroll
    for (int j = 0; j < CHUNKA / 256; ++j) {
        int p = p0 + tid + j * 256;
        if (p < P) {
            atomicAdd(&cv[pv[p] >> SH_V], 1);
            atomicAdd(&ce[pe[p] >> SH_E], 1);
        }
    }
    __syncthreads();
    if (cv[tid]) atomicAdd(&btot_v[tid], cv[tid]);
    if (ce[tid]) atomicAdd(&btot_e[tid], ce[tid]);
}

// in-place exclusive scan, a[n]=total (single block, n <= 1024 here)
__global__ void k_scan_small(int* __restrict__ a, int n) {
    __shared__ int wsum[16];
    __shared__ int carry_s;
    int tid = threadIdx.x;
    int lane = tid & 63;
    int w = tid >> 6;
    if (tid == 0) carry_s = 0;
    __syncthreads();
    for (int base = 0; base < n; base += 1024) {
        int i = base + tid;
        int v = (i < n) ? a[i] : 0;
        int x = v;
        #pragma unroll
        for (int off = 1; off < 64; off <<= 1) {
            int t = __shfl_up(x, off);
            if (lane >= off) x += t;
        }
        if (lane == 63) wsum[w] = x;
        __syncthreads();
        int woff = 0;
        for (int k = 0; k < w; ++k) woff += wsum[k];
        int carry = carry_s;
        if (i < n) a[i] = carry + woff + x - v;
        int tot = 0;
        for (int k = 0; k < 16; ++k) tot += wsum[k];
        __syncthreads();
        if (tid == 0) carry_s = carry + tot;
        __syncthreads();
    }
    if (tid == 0) a[n] = carry_s;
}

// phase A: scatter pairs into bucket-grouped arrays (per-(block,bucket) contiguous windows)
__global__ void k_scatter2way(const int* __restrict__ pv, const int* __restrict__ pe,
                              const int* __restrict__ bstart_v, const int* __restrict__ bstart_e,
                              int* __restrict__ cur_v, int* __restrict__ cur_e,
                              uint2* __restrict__ sorted_v, uint2* __restrict__ sorted_e, int P) {
    __shared__ int cv[256], ce[256], posv[256], pose[256];
    int tid = threadIdx.x;
    cv[tid] = 0; ce[tid] = 0;
    __syncthreads();
    int p0 = blockIdx.x * CHUNKA;
    int kv[CHUNKA / 256], ke[CHUNKA / 256];
    #pragma unroll
    for (int j = 0; j < CHUNKA / 256; ++j) {
        int p = p0 + tid + j * 256;
        if (p < P) {
            kv[j] = pv[p];
            ke[j] = pe[p];
            atomicAdd(&cv[kv[j] >> SH_V], 1);
            atomicAdd(&ce[ke[j] >> SH_E], 1);
        } else {
            kv[j] = -1;
            ke[j] = -1;
        }
    }
    __syncthreads();
    if (cv[tid]) posv[tid] = bstart_v[tid] + atomicAdd(&cur_v[tid], cv[tid]);
    if (ce[tid]) pose[tid] = bstart_e[tid] + atomicAdd(&cur_e[tid], ce[tid]);
    __syncthreads();
    #pragma unroll
    for (int j = 0; j < CHUNKA / 256; ++j) {
        if (kv[j] >= 0) {
            int iv = atomicAdd(&posv[kv[j] >> SH_V], 1);
            sorted_v[iv] = make_uint2((unsigned)kv[j], (unsigned)ke[j]);
            int ie = atomicAdd(&pose[ke[j] >> SH_E], 1);
            sorted_e[ie] = make_uint2((unsigned)ke[j], (unsigned)kv[j]);
        }
    }
}

// phase B: per-bucket CSR build. One block per bucket.
template <int SUBD, int SH>
__global__ void k_build(const uint2* __restrict__ sorted, const int* __restrict__ bstart,
                        int* __restrict__ start_out, int* __restrict__ deg_out,
                        int* __restrict__ csr_out, int D) {
    __shared__ int deg[SUBD], pos[SUBD];
    int b = blockIdx.x;
    int tid = threadIdx.x;
    int base_key = b << SH;
    int s0 = bstart[b];
    int cnt = bstart[b + 1] - s0;
    for (int k = tid; k < SUBD; k += 256) deg[k] = 0;
    __syncthreads();
    for (int i = tid; i < cnt; i += 256)
        atomicAdd(&deg[(int)sorted[s0 + i].x - base_key], 1);
    __syncthreads();
    if (tid < 64) {
        int carry = 0;
        for (int base = 0; base < SUBD; base += 64) {
            int d = deg[base + tid];
            int x = d;
            #pragma unroll
            for (int off = 1; off < 64; off <<= 1) {
                int t = __shfl_up(x, off);
                if (tid >= off) x += t;
            }
            pos[base + tid] = carry + x - d;
            carry += __shfl(x, 63);
        }
    }
    __syncthreads();
    for (int k = tid; k < SUBD; k += 256) {
        int key = base_key + k;
        if (key < D) {
            start_out[key] = s0 + pos[k];
            deg_out[key] = deg[k];
        }
    }
    __syncthreads();
    for (int i = tid; i < cnt; i += 256) {
        uint2 pr = sorted[s0 + i];
        int loc = (int)pr.x - base_key;
        int idx = atomicAdd(&pos[loc], 1);
        csr_out[s0 + idx] = (int)pr.y;
    }
}

// ---------------- weight prep ----------------

__global__ void k_wav(const float* __restrict__ W1, const float* __restrict__ b1,
                      const float* __restrict__ av1, float* __restrict__ wav,
                      float* __restrict__ bav) {
    int h = blockIdx.x;
    int k = threadIdx.x;
    float s = 0.f;
    for (int j = 0; j < DH; ++j) s += W1[(size_t)(h * DIN + k) * DH + j] * av1[h * DH + j];
    wav[h * DIN + k] = s;
    if (k == 0) {
        float t = 0.f;
        for (int j = 0; j < DH; ++j) t += b1[h * DH + j] * av1[h * DH + j];
        bav[h] = t;
    }
}

__global__ void k_build_wcatT(const float* __restrict__ W1, u16* __restrict__ WcatT) {
    int idx = blockIdx.x * 256 + threadIdx.x;
    if (idx >= 256 * DIN) return;
    int c = idx >> 7, k = idx & 127;
    int h = c >> 6, j = c & 63;
    WcatT[c * DIN + k] = f2bf(W1[((size_t)h * DIN + k) * DH + j]);
}

__global__ void k_build_w2T(const float* __restrict__ W2, u16* __restrict__ W2T) {
    int idx = blockIdx.x * 256 + threadIdx.x;
    if (idx >= 48 * DCAT) return;
    int c = idx >> 9, k = idx & 511;
    float v = (c < NC) ? W2[(size_t)k * NC + c] : 0.f;
    W2T[c * DCAT + k] = f2bf(v);
}

// ---------------- conversion + node attention term (layer 1), both inputs ----------------
// Xbi interleaved [N][2][128]; sv8[n*8 + h*2 + z]
__global__ void k_conv(const float* __restrict__ X0, const float* __restrict__ X1,
                       const float* __restrict__ wav, const float* __restrict__ bav,
                       u16* __restrict__ Xbi, float* __restrict__ sv8, int N) {
    int wave = (blockIdx.x * blockDim.x + threadIdx.x) >> 6;
    int lane = threadIdx.x & 63;
    if (wave >= N) return;
    int xz = blockIdx.y;
    const float* X = xz ? X1 : X0;
    float2 a = *(const float2*)(X + (size_t)wave * DIN + lane * 2);
    unsigned int packed = (unsigned int)f2bf(a.x) | ((unsigned int)f2bf(a.y) << 16);
    *(unsigned int*)(Xbi + (size_t)wave * 256 + xz * 128 + lane * 2) = packed;
    float s[NH];
    #pragma unroll
    for (int h = 0; h < NH; ++h) {
        float2 wv = *(const float2*)(wav + h * DIN + lane * 2);
        float t = a.x * wv.x + a.y * wv.y;
        #pragma unroll
        for (int off = 32; off >= 1; off >>= 1) t += __shfl_xor(t, off);
        s[h] = t;
    }
    if (lane == 0) {
        #pragma unroll
        for (int h = 0; h < NH; ++h) sv8[(size_t)wave * 8 + h * 2 + xz] = s[h] + bav[h];
    }
}

// ---------------- edge mean (bf16, D=128), both inputs, unroll-3 pipelined ----------------
__global__ void k_edge_mean1(const u16* __restrict__ Xbi, const int* __restrict__ start_e,
                             const int* __restrict__ deg_e, const int* __restrict__ csr_e_v,
                             u16* __restrict__ Xbar0, u16* __restrict__ Xbar1, int E) {
    int wave = (blockIdx.x * blockDim.x + threadIdx.x) >> 6;
    int lane = threadIdx.x & 63;
    if (wave >= E) return;
    int s = start_e[wave], t = s + deg_e[wave];
    int q = lane >> 4, c = lane & 15;
    float a0[8], a1[8];
    #pragma unroll
    for (int j = 0; j < 8; ++j) { a0[j] = 0.f; a1[j] = 0.f; }
    int i = s + q;
    u16x8 y0A = {0}, y1A = {0}, y0B = {0}, y1B = {0}, y0C = {0}, y1C = {0};
#define EM1_LOAD(Y0, Y1, IDX) { int v_ = csr_e_v[IDX]; \
        const u16* yp_ = Xbi + (size_t)v_ * 256 + c * 8; \
        Y0 = *(const u16x8*)yp_; Y1 = *(const u16x8*)(yp_ + 128); }
#define EM1_CONSUME(Y0, Y1) { \
        _Pragma("unroll") \
        for (int j = 0; j < 8; ++j) { a0[j] += bf2f(Y0[j]); a1[j] += bf2f(Y1[j]); } }
    if (i < t) EM1_LOAD(y0A, y1A, i);
    if (i + 4 < t) EM1_LOAD(y0B, y1B, i + 4);
    if (i + 8 < t) EM1_LOAD(y0C, y1C, i + 8);
    for (; i + 8 < t; i += 12) {
        EM1_CONSUME(y0A, y1A);
        if (i + 12 < t) EM1_LOAD(y0A, y1A, i + 12);
        EM1_CONSUME(y0B, y1B);
        if (i + 16 < t) EM1_LOAD(y0B, y1B, i + 16);
        EM1_CONSUME(y0C, y1C);
        if (i + 20 < t) EM1_LOAD(y0C, y1C, i + 20);
    }
    if (i < t) EM1_CONSUME(y0A, y1A);
    if (i + 4 < t) EM1_CONSUME(y0B, y1B);
#undef EM1_LOAD
#undef EM1_CONSUME
    #pragma unroll
    for (int j = 0; j < 8; ++j) {
        a0[j] += __shfl_xor(a0[j], 16);
        a0[j] += __shfl_xor(a0[j], 32);
        a1[j] += __shfl_xor(a1[j], 16);
        a1[j] += __shfl_xor(a1[j], 32);
    }
    int deg = t - s;
    float inv = 1.f / (float)(deg > 1 ? deg : 1);
    if (q == 0) {
        u16x8 r0, r1;
        #pragma unroll
        for (int j = 0; j < 8; ++j) { r0[j] = f2bf(a0[j] * inv); r1[j] = f2bf(a1[j] * inv); }
        *(u16x8*)(Xbar0 + (size_t)wave * DIN + c * 8) = r0;
        *(u16x8*)(Xbar1 + (size_t)wave * DIN + c * 8) = r1;
    }
}

// ---------------- MFMA GEMM with fused row-dot epilogue ----------------
// DOTMODE 0: none; 1: per-head dots -> dout[row*8 + head*2 + z]; 2: single dot -> dout[row]
template <int KDIM, int NTILES, int DOTMODE>
__global__ __launch_bounds__(256) void k_gemm_mfma(const u16* __restrict__ A0,
                                                   const u16* __restrict__ A1, int M,
                                                   const u16* __restrict__ Bt,
                                                   const float* __restrict__ bias,
                                                   u16* __restrict__ out0, u16* __restrict__ out1,
                                                   int ldo, int ncols,
                                                   const float* __restrict__ dvec,
                                                   float* __restrict__ dout) {
    constexpr int LDB = KDIM + 8;
    __shared__ u16 Bs[NTILES * 16 * LDB];
    const u16* A = blockIdx.z ? A1 : A0;
    u16* out = blockIdx.z ? out1 : out0;
    int tid = threadIdx.x;
    int colbase = blockIdx.y * NTILES * 16;
    const u16* Btblk = Bt + (size_t)colbase * KDIM;
    for (int idx = tid * 4; idx < NTILES * 16 * KDIM; idx += 256 * 4) {
        int c = idx / KDIM, k = idx % KDIM;
        *(u16x4*)&Bs[c * LDB + k] = *(const u16x4*)(Btblk + c * KDIM + k);
    }
    __syncthreads();
    int w = tid >> 6, lane = tid & 63;
    int r0 = blockIdx.x * 64 + w * 16;
    int arow = r0 + (lane & 15);
    bool avalid = arow < M;
    const u16* ap = A + (size_t)arow * KDIM + (lane >> 4) * 8;
    f32x4 acc[NTILES];
    #pragma unroll
    for (int nt = 0; nt < NTILES; ++nt) acc[nt] = (f32x4){0.f, 0.f, 0.f, 0.f};
    #pragma unroll
    for (int k0 = 0; k0 < KDIM; k0 += 32) {
        bf16x8 a = (bf16x8)(short)0;
        if (avalid) a = *(const bf16x8*)(ap + k0);
        #pragma unroll
        for (int nt = 0; nt < NTILES; ++nt) {
            bf16x8 b = *(const bf16x8*)&Bs[(nt * 16 + (lane & 15)) * LDB + k0 + (lane >> 4) * 8];
            acc[nt] = __builtin_amdgcn_mfma_f32_16x16x32_bf16(a, b, acc[nt], 0, 0, 0);
        }
    }
    #pragma unroll
    for (int j = 0; j < 4; ++j) {
        int row = r0 + (lane >> 4) * 4 + j;
        float pA = 0.f, pB = 0.f;
        #pragma unroll
        for (int nt = 0; nt < NTILES; ++nt) {
            int col = colbase + nt * 16 + (lane & 15);
            bool cok = col < ncols;
            float val = cok ? acc[nt][j] + bias[col] : 0.f;
            if (DOTMODE == 1) {
                float dv = dvec[col];
                if (nt < NTILES / 2) pA += val * dv; else pB += val * dv;
            } else if (DOTMODE == 2) {
                pA += cok ? val * dvec[col] : 0.f;
            }
            if (row < M && cok) out[(size_t)row * ldo + col] = f2bf(val);
        }
        if (DOTMODE) {
            pA += __shfl_xor(pA, 1);
            pA += __shfl_xor(pA, 2);
            pA += __shfl_xor(pA, 4);
            pA += __shfl_xor(pA, 8);
            if (DOTMODE == 1) {
                pB += __shfl_xor(pB, 1);
                pB += __shfl_xor(pB, 2);
                pB += __shfl_xor(pB, 4);
                pB += __shfl_xor(pB, 8);
            }
            if ((lane & 15) == 0 && row < M) {
                if (DOTMODE == 1) {
                    int hbase = blockIdx.y * 2;
                    int z = blockIdx.z;
                    dout[(size_t)row * 8 + hbase * 2 + z] = pA;
                    dout[(size_t)row * 8 + (hbase + 1) * 2 + z] = pB;
                } else {
                    dout[row] = pA;
                }
            }
        }
    }
}

// ---------------- fused node pass (layer 1), both inputs, simple loop ----------------
// Ycat interleaved [E,512]; se8[e*8+h*2+z]; no-max softmax (scores bounded by construction).
__global__ void k_node_pass1(const u16* __restrict__ Ycat, const float* __restrict__ se8,
                             const float* __restrict__ sv8, const int* __restrict__ start_v,
                             const int* __restrict__ deg_v, const int* __restrict__ csr_v_e,
                             u16* __restrict__ hbuf, int N) {
    int wave = (blockIdx.x * blockDim.x + threadIdx.x) >> 6;
    int lane = threadIdx.x & 63;
    if (wave >= N) return;
    int p0 = start_v[wave], p1 = p0 + deg_v[wave];
    int g = lane >> 5;
    int c = lane & 31;
    int h = c >> 3;
    u16* orow = hbuf + (size_t)wave * DCAT + c * 8;
    if (p1 == p0) {
        if (g == 0) {
            u16x8 z8 = {0, 0, 0, 0, 0, 0, 0, 0};
            *(u16x8*)orow = z8;
            *(u16x8*)(orow + 256) = z8;
        }
        return;
    }
    float sv0 = sv8[(size_t)wave * 8 + h * 2];
    float sv1 = sv8[(size_t)wave * 8 + h * 2 + 1];
    float den0 = 0.f, den1 = 0.f;
    float a0[8], a1[8];
    #pragma unroll
    for (int j = 0; j < 8; ++j) { a0[j] = 0.f; a1[j] = 0.f; }
    for (int i = p0 + g; i < p1; i += 2) {
        int e = csr_v_e[i];
        float2 s2 = *(const float2*)(se8 + e * 8 + h * 2);
        float x0 = s2.x + sv0;
        float x1 = s2.y + sv1;
        x0 = fmaxf(x0, 0.2f * x0);
        x1 = fmaxf(x1, 0.2f * x1);
        float e0 = __expf(x0);
        float e1 = __expf(x1);
        den0 += e0;
        den1 += e1;
        const u16* yp = Ycat + (size_t)e * 512 + c * 8;
        u16x8 q0 = *(const u16x8*)yp;
        u16x8 q1 = *(const u16x8*)(yp + 256);
        #pragma unroll
        for (int j = 0; j < 8; ++j) { a0[j] += e0 * bf2f(q0[j]); a1[j] += e1 * bf2f(q1[j]); }
    }
    den0 += __shfl_xor(den0, 32);
    den1 += __shfl_xor(den1, 32);
    #pragma unroll
    for (int j = 0; j < 8; ++j) {
        a0[j] += __shfl_xor(a0[j], 32);
        a1[j] += __shfl_xor(a1[j], 32);
    }
    float i0 = 1.f / den0, i1 = 1.f / den1;
    u16x8 r0, r1;
    #pragma unroll
    for (int j = 0; j < 8; ++j) {
        float o0 = a0[j] * i0;
        float o1 = a1[j] * i1;
        o0 = o0 > 0.f ? o0 : __expf(o0) - 1.f;
        o1 = o1 > 0.f ? o1 : __expf(o1) - 1.f;
        r0[j] = f2bf(o0);
        r1[j] = f2bf(o1);
    }
    if (g == 0) {
        *(u16x8*)orow = r0;
        *(u16x8*)(orow + 256) = r1;
    }
}

// ---------------- layer 2 small kernels ----------------

__global__ void k_edge_mean2(const u16* __restrict__ Xp2b, const int* __restrict__ start_e,
                             const int* __restrict__ deg_ea, const int* __restrict__ csr_e_v,
                             u16* __restrict__ Y2b, const float* __restrict__ ae2,
                             float* __restrict__ se2, int E) {
    int wave = (blockIdx.x * blockDim.x + threadIdx.x) >> 6;
    int lane = threadIdx.x & 63;
    if (wave >= E) return;
    int s = start_e[wave], t = s + deg_ea[wave];
    int g = lane >> 4, c = lane & 15;
    bool act = c < 10;
    float acc[4];
    #pragma unroll
    for (int j = 0; j < 4; ++j) acc[j] = 0.f;
    for (int i = s + g; i < t; i += 4) {
        int v = csr_e_v[i];
        if (act) {
            u16x4 y = *(const u16x4*)(Xp2b + (size_t)v * NC + c * 4);
            acc[0] += bf2f(y.x);
            acc[1] += bf2f(y.y);
            acc[2] += bf2f(y.z);
            acc[3] += bf2f(y.w);
        }
    }
    #pragma unroll
    for (int j = 0; j < 4; ++j) {
        acc[j] += __shfl_xor(acc[j], 16);
        acc[j] += __shfl_xor(acc[j], 32);
    }
    int deg = t - s;
    float inv = 1.f / (float)(deg > 1 ? deg : 1);
    float p = 0.f;
    if (act) {
        float4 ae = *(const float4*)(ae2 + c * 4);
        float y0 = acc[0] * inv, y1 = acc[1] * inv, y2 = acc[2] * inv, y3 = acc[3] * inv;
        p = y0 * ae.x + y1 * ae.y + y2 * ae.z + y3 * ae.w;
        if (g == 0) {
            u16x4 r = {f2bf(y0), f2bf(y1), f2bf(y2), f2bf(y3)};
            *(u16x4*)(Y2b + (size_t)wave * NC + c * 4) = r;
        }
    }
    #pragma unroll
    for (int off = 8; off >= 1; off >>= 1) p += __shfl_xor(p, off);
    if (lane == 0) se2[wave] = p;
}

__global__ void k_node_pass2(const u16* __restrict__ Y2b, const float* __restrict__ se2,
                             const float* __restrict__ sv2, const int* __restrict__ start_v,
                             const int* __restrict__ deg_va, const int* __restrict__ csr_v_e,
                             float* __restrict__ out, int N) {
    int wave = (blockIdx.x * blockDim.x + threadIdx.x) >> 6;
    int lane = threadIdx.x & 63;
    if (wave >= N) return;
    int s = start_v[wave], t = s + deg_va[wave];
    int g = lane >> 4, c = lane & 15;
    bool act = c < 10;
    float* orow = out + (size_t)wave * NC;
    if (t == s) {
        if (g == 0 && act) *(float4*)(orow + c * 4) = make_float4(0.f, 0.f, 0.f, 0.f);
        return;
    }
    float svv = sv2[wave];
    float den = 0.f;
    float acc[4];
    #pragma unroll
    for (int j = 0; j < 4; ++j) acc[j] = 0.f;
    for (int i = s + g; i < t; i += 4) {
        int e = csr_v_e[i];
        float x = se2[e] + svv;
        x = fmaxf(x, 0.2f * x);
        float ex = __expf(x);
        den += ex;
        if (act) {
            u16x4 y = *(const u16x4*)(Y2b + (size_t)e * NC + c * 4);
            acc[0] += ex * bf2f(y.x);
            acc[1] += ex * bf2f(y.y);
            acc[2] += ex * bf2f(y.z);
            acc[3] += ex * bf2f(y.w);
        }
    }
    den += __shfl_xor(den, 16);
    den += __shfl_xor(den, 32);
    #pragma unroll
    for (int j = 0; j < 4; ++j) {
        acc[j] += __shfl_xor(acc[j], 16);
        acc[j] += __shfl_xor(acc[j], 32);
    }
    if (g == 0 && act) {
        float inv = 1.f / den;
        float4 o;
        float* op = &o.x;
        #pragma unroll
        for (int j = 0; j < 4; ++j) {
            float v = acc[j] * inv;
            op[j] = v > 0.f ? v : __expf(v) - 1.f;
        }
        *(float4*)(orow + c * 4) = o;
    }
}

// ---------------- launcher ----------------
extern "C" void kernel_launch(void* const* d_in, const int* in_sizes, int n_in,
                              void* d_out, int out_size, void* d_ws, size_t ws_size,
                              hipStream_t stream) {
    const float* x0 = (const float*)d_in[0];
    const float* x1 = (const float*)d_in[1];
    const float* W1 = (const float*)d_in[2];
    const float* b1 = (const float*)d_in[3];
    const float* ae1 = (const float*)d_in[4];
    const float* av1 = (const float*)d_in[5];
    const float* W2 = (const float*)d_in[6];
    const float* b2 = (const float*)d_in[7];
    const float* ae2 = (const float*)d_in[8];
    const float* av2 = (const float*)d_in[9];
    const int* pe = (const int*)d_in[10];
    const int* pv = (const int*)d_in[11];

    const int N = in_sizes[0] / DIN;  // 100000
    const int P = in_sizes[10];       // 1600000
    const int E = E_CONST;            // 20000
    const int NBKT_V = (N + SUBD_V - 1) / SUBD_V;   // 196
    const int NBKT_E = (E + SUBD_E - 1) / SUBD_E;   // 157

    char* base = (char*)d_ws;
    auto alloc = [&](size_t bytes) -> void* {
        void* p = (void*)base;
        base += (bytes + 255) & ~(size_t)255;
        return p;
    };
    u16* Xbi = (u16*)alloc((size_t)N * 256 * 2);
    u16* hbuf = (u16*)alloc((size_t)N * DCAT * 2);
    u16* Xbar0 = (u16*)alloc((size_t)E * DIN * 2);
    u16* Xbar1 = (u16*)alloc((size_t)E * DIN * 2);
    u16* Ycat = (u16*)alloc((size_t)E * 512 * 2);
    u16* Xp2b = (u16*)alloc((size_t)N * NC * 2);
    u16* Y2b = (u16*)alloc((size_t)E * NC * 2);
    float* se8 = (float*)alloc((size_t)E * 8 * 4);
    float* se2 = (float*)alloc((size_t)E * 4);
    float* sv8 = (float*)alloc((size_t)N * 8 * 4);
    float* sv2 = (float*)alloc((size_t)N * 4);
    float* wav = (float*)alloc((size_t)NH * DIN * 4);
    float* bav = (float*)alloc((size_t)NH * 4);
    u16* WcatT = (u16*)alloc((size_t)256 * DIN * 2);
    u16* W2T = (u16*)alloc((size_t)48 * DCAT * 2);
    uint2* sorted_v = (uint2*)alloc((size_t)P * 8);
    uint2* sorted_e = (uint2*)alloc((size_t)P * 8);
    int* start_v = (int*)alloc((size_t)N * 4);
    int* deg_v = (int*)alloc((size_t)N * 4);
    int* start_e = (int*)alloc((size_t)E * 4);
    int* deg_e = (int*)alloc((size_t)E * 4);
    int* csr_v_e = (int*)alloc((size_t)P * 4);
    int* csr_e_v = (int*)alloc((size_t)P * 4);
    char* zstart = base;
    int* bstart_v = (int*)alloc((size_t)(NBKT_V + 1) * 4);
    int* bstart_e = (int*)alloc((size_t)(NBKT_E + 1) * 4);
    int* cur_v = (int*)alloc((size_t)256 * 4);
    int* cur_e = (int*)alloc((size_t)256 * 4);
    size_t zbytes = (size_t)(base - zstart);

    if ((size_t)(base - (char*)d_ws) > ws_size) return;

    hipMemsetAsync(zstart, 0, zbytes, stream);

    dim3 b256(256);
    int nA = (P + CHUNKA - 1) / CHUNKA;   // 391
    k_hist2<<<nA, b256, 0, stream>>>(pv, pe, bstart_v, bstart_e, P);
    k_scan_small<<<1, 1024, 0, stream>>>(bstart_v, NBKT_V);
    k_scan_small<<<1, 1024, 0, stream>>>(bstart_e, NBKT_E);
    k_scatter2way<<<nA, b256, 0, stream>>>(pv, pe, bstart_v, bstart_e, cur_v, cur_e,
                                           sorted_v, sorted_e, P);
    k_build<SUBD_V, SH_V><<<NBKT_V, b256, 0, stream>>>(sorted_v, bstart_v, start_v, deg_v,
                                                       csr_v_e, N);
    k_build<SUBD_E, SH_E><<<NBKT_E, b256, 0, stream>>>(sorted_e, bstart_e, start_e, deg_e,
                                                       csr_e_v, E);

    k_wav<<<NH, DIN, 0, stream>>>(W1, b1, av1, wav, bav);
    k_build_wcatT<<<(256 * DIN + 255) / 256, b256, 0, stream>>>(W1, WcatT);
    k_build_w2T<<<(48 * DCAT + 255) / 256, b256, 0, stream>>>(W2, W2T);

    int gN4 = (N + 3) / 4;
    int gE4 = (E + 3) / 4;
    dim3 gconv(gN4, 2);
    k_conv<<<gconv, b256, 0, stream>>>(x0, x1, wav, bav, Xbi, sv8, N);

    k_edge_mean1<<<gE4, b256, 0, stream>>>(Xbi, start_e, deg_e, csr_e_v, Xbar0, Xbar1, E);
    dim3 g1((E + 63) / 64, 2, 2);
    k_gemm_mfma<DIN, 8, 1><<<g1, b256, 0, stream>>>(Xbar0, Xbar1, E, WcatT, b1,
                                                    Ycat, Ycat + 256, 512, 256, ae1, se8);
    k_node_pass1<<<gN4, b256, 0, stream>>>(Ycat, se8, sv8, start_v, deg_v, csr_v_e, hbuf, N);

    dim3 g2((N + 63) / 64, 1, 1);
    k_gemm_mfma<DCAT, 3, 2><<<g2, b256, 0, stream>>>(hbuf, hbuf, N, W2T, b2, Xp2b, Xp2b,
                                                     NC, NC, av2, sv2);
    k_edge_mean2<<<gE4, b256, 0, stream>>>(Xp2b, start_e, deg_e, csr_e_v, Y2b, ae2, se2, E);
    k_node_pass2<<<gN4, b256, 0, stream>>>(Y2b, se2, sv2, start_v, deg_v, csr_v_e,
                                           (float*)d_out, N);
}